// Round 5
// baseline (571.368 us; speedup 1.0000x reference)
//
#include <hip/hip_runtime.h>

#define BATCH 8
#define SEQ   4096
#define CH    64
#define KDIM  192   // 3 taps x 64 channels
#define LOG2E 1.44269504f

typedef __attribute__((ext_vector_type(8))) short bf16x8;    // 8 bf16 in 4 VGPRs
typedef __attribute__((ext_vector_type(4))) float f32x4;

#define MFMA16(a, b, c) __builtin_amdgcn_mfma_f32_16x16x32_bf16(a, b, c, 0, 0, 0)

__device__ __forceinline__ unsigned short f2bf(float f) {
    union { float f; unsigned int u; } v; v.f = f;
    unsigned int r = v.u + 0x7fffu + ((v.u >> 16) & 1u);   // RNE
    return (unsigned short)(r >> 16);
}
__device__ __forceinline__ float bf2f(unsigned short h) {
    union { float f; unsigned int u; } v; v.u = ((unsigned int)h) << 16;
    return v.f;
}
// pack two f32 -> one u32 of 2 bf16 (lo = first arg), guide T12 recipe
__device__ __forceinline__ unsigned cvtpk(float lo, float hi) {
    unsigned r;
    asm volatile("v_cvt_pk_bf16_f32 %0, %1, %2" : "=v"(r) : "v"(lo), "v"(hi));
    return r;
}

// ---------------------------------------------------------------------------
// K0: fold 1x1 convs into the shared 3-tap conv; emit TRANSPOSED hi/lo split
// weights for the MFMA conv. grid: 9 blocks, 256 threads.  (R2-passing)
// ---------------------------------------------------------------------------
__global__ void combine_w_kernel(const float* __restrict__ wq, const float* __restrict__ bq,
                                 const float* __restrict__ wk, const float* __restrict__ bk,
                                 const float* __restrict__ wv, const float* __restrict__ bv,
                                 const float* __restrict__ wd,
                                 unsigned short* __restrict__ Wth, unsigned short* __restrict__ Wtl,
                                 float* __restrict__ bbp) {
    int T = blockIdx.x / 3, t = blockIdx.x % 3;
    const float* w1 = (T == 0) ? wq : (T == 1) ? wk : wv;
    const float* b1 = (T == 0) ? bq : (T == 1) ? bk : bv;
    const float* wdt = wd + t * CH * CH;
    for (int idx = threadIdx.x; idx < CH * CH; idx += blockDim.x) {
        int i = idx >> 6, c = idx & 63;
        float acc = 0.f;
        for (int m = 0; m < CH; ++m) acc = fmaf(w1[i * CH + m], wdt[m * CH + c], acc);
        unsigned short h = f2bf(acc);
        size_t o = ((size_t)(T * CH + c)) * KDIM + t * CH + i;
        Wth[o] = h;
        Wtl[o] = f2bf(acc - bf2f(h));
    }
    if (threadIdx.x < CH) {
        int c = threadIdx.x;
        float acc = 0.f;
        for (int m = 0; m < CH; ++m) acc = fmaf(b1[m], wdt[m * CH + c], acc);
        bbp[(T * 3 + t) * CH + c] = acc;
    }
}

// ---------------------------------------------------------------------------
// K1: MFMA conv (R2-passing structure). Q additionally scaled by log2(e) so
// attention can use exp2 (linear fold, exact).
// ---------------------------------------------------------------------------
__global__ __launch_bounds__(256) void conv_mfma_kernel(
        const float* __restrict__ Q, const float* __restrict__ K, const float* __restrict__ V,
        const unsigned short* __restrict__ Wth, const unsigned short* __restrict__ Wtl,
        const float* __restrict__ bbp, const float* __restrict__ bd,
        unsigned short* __restrict__ Qh, unsigned short* __restrict__ Ql,
        unsigned short* __restrict__ Kh, unsigned short* __restrict__ Kl,
        unsigned short* __restrict__ Vt) {
    int T = blockIdx.y;
    const float* X = (T == 0) ? Q : (T == 1) ? K : V;
    int rowblk = blockIdx.x;          // 0..511
    int b  = rowblk >> 6;
    int l0 = (rowblk & 63) << 6;

    __shared__ unsigned short xh[66][64];
    __shared__ unsigned short xl[66][64];

    int tid = threadIdx.x;
    for (int q4 = tid; q4 < 66 * 16; q4 += 256) {
        int row = q4 >> 4, i = (q4 & 15) << 2;
        int gl = l0 + row - 1;
        float4 v = make_float4(0.f, 0.f, 0.f, 0.f);
        if (gl >= 0 && gl < SEQ) v = *(const float4*)(X + ((size_t)b * SEQ + gl) * CH + i);
        unsigned short h0 = f2bf(v.x), h1 = f2bf(v.y), h2 = f2bf(v.z), h3 = f2bf(v.w);
        unsigned short e0 = f2bf(v.x - bf2f(h0)), e1 = f2bf(v.y - bf2f(h1));
        unsigned short e2 = f2bf(v.z - bf2f(h2)), e3 = f2bf(v.w - bf2f(h3));
        int sw = i ^ ((row & 7) << 3);
        uint2 hp = { (unsigned)h0 | ((unsigned)h1 << 16), (unsigned)h2 | ((unsigned)h3 << 16) };
        uint2 lp = { (unsigned)e0 | ((unsigned)e1 << 16), (unsigned)e2 | ((unsigned)e3 << 16) };
        *(uint2*)&xh[row][sw] = hp;
        *(uint2*)&xl[row][sw] = lp;
    }
    __syncthreads();

    int wave = tid >> 6, lane = tid & 63;
    int g = lane >> 4, cc = lane & 15;
    int wrow0 = wave << 4;

    bf16x8 ah[6], al[6];
#pragma unroll
    for (int kk = 0; kk < 6; ++kk) {
        int t = kk >> 1;
        int u = wrow0 + cc + t;
        int blk = (((kk & 1) * 4 + g) ^ (u & 7));
        ah[kk] = *(const bf16x8*)&xh[u][blk << 3];
        al[kk] = *(const bf16x8*)&xl[u][blk << 3];
    }

    for (int nt = 0; nt < 4; ++nt) {
        int col = nt * 16 + cc;
        const unsigned short* wbh = Wth + ((size_t)(T * CH + col)) * KDIM;
        const unsigned short* wbl = Wtl + ((size_t)(T * CH + col)) * KDIM;
        f32x4 acc = {0.f, 0.f, 0.f, 0.f};
#pragma unroll
        for (int kk = 0; kk < 6; ++kk) {
            bf16x8 bh = *(const bf16x8*)(wbh + kk * 32 + g * 8);
            bf16x8 bl = *(const bf16x8*)(wbl + kk * 32 + g * 8);
            acc = MFMA16(ah[kk], bh, acc);
            acc = MFMA16(al[kk], bh, acc);
            acc = MFMA16(ah[kk], bl, acc);
        }
        float bias = bd[col] + bbp[(T * 3 + 0) * CH + col] + bbp[(T * 3 + 1) * CH + col]
                   + bbp[(T * 3 + 2) * CH + col];
#pragma unroll
        for (int r = 0; r < 4; ++r) {
            int gl = l0 + wrow0 + g * 4 + r;
            float v = acc[r] + bias;
            if (gl == 0)       v -= bbp[(T * 3 + 0) * CH + col];
            if (gl == SEQ - 1) v -= bbp[(T * 3 + 2) * CH + col];
            if (T == 0) {
                float vq = v * LOG2E;            // fold ln2 into Q -> attn uses exp2
                unsigned short h = f2bf(vq);
                Qh[((size_t)b * SEQ + gl) * CH + col] = h;
                Ql[((size_t)b * SEQ + gl) * CH + col] = f2bf(vq - bf2f(h));
            } else if (T == 1) {
                unsigned short h = f2bf(v);
                Kh[((size_t)b * SEQ + gl) * CH + col] = h;
                Kl[((size_t)b * SEQ + gl) * CH + col] = f2bf(v - bf2f(h));
            } else {
                Vt[((size_t)b * CH + col) * SEQ + gl] = f2bf(v);
            }
        }
    }
}

// ---------------------------------------------------------------------------
// K2: flash attention — swapped QK^T with PERMUTED KEY ROWS, 16x16x32 only
// (all operand mappings R1/R2-verified), zero LDS, zero common-path shuffles.
//
// Sub-tile 0 loads K rows kb + (c>>2)*8+(c&3)  (octet lows),
// sub-tile 1 loads      kb + (c>>2)*8+(c&3)+4  (octet highs), so
//   s0[r] = S[query c][kb + g*8 + r],  s1[r] = S[query c][kb + g*8 + 4 + r]
// i.e. lane (c,g) holds exactly keys g*8..g*8+7 of query c — which IS the
// PV A-fragment layout (row=c, k=g*8+i). P packs in-register via cvt_pk.
// Softmax max kept per-query-consistent via a rare __any-triggered reduce.
// grid: 512*NS blocks (b = bid&7 XCD-pinned), 4 waves x 16 queries.
// ---------------------------------------------------------------------------
__global__ __launch_bounds__(256) void attn_kernel(
        const unsigned short* __restrict__ Qh, const unsigned short* __restrict__ Ql,
        const unsigned short* __restrict__ Kh, const unsigned short* __restrict__ Kl,
        const unsigned short* __restrict__ Vt,
        float* __restrict__ Opart, float* __restrict__ Mp, float* __restrict__ Lp,
        int seg_len) {
    int bid  = blockIdx.x;
    int s    = bid >> 9;
    int b    = bid & 7;
    int qt   = (bid >> 3) & 63;
    int wave = threadIdx.x >> 6;
    int lane = threadIdx.x & 63;
    int c = lane & 15, g = lane >> 4;
    int q0 = qt * 64 + wave * 16;

    // Q B-fragments: col = query c, k = d = ch*32 + g*8 + i
    bf16x8 qbh[2], qbl[2];
    {
        const size_t qoff = ((size_t)b * SEQ + q0 + c) * CH + g * 8;
        qbh[0] = *(const bf16x8*)(Qh + qoff);
        qbh[1] = *(const bf16x8*)(Qh + qoff + 32);
        qbl[0] = *(const bf16x8*)(Ql + qoff);
        qbl[1] = *(const bf16x8*)(Ql + qoff + 32);
    }

    f32x4 o0 = {0,0,0,0}, o1 = {0,0,0,0}, o2 = {0,0,0,0}, o3 = {0,0,0,0};
    float mreg = -1e30f, lreg = 0.f;

    const unsigned short* Kbh = Kh + (size_t)b * SEQ * CH;
    const unsigned short* Kbl = Kl + (size_t)b * SEQ * CH;
    const unsigned short* Vb  = Vt + (size_t)b * CH * SEQ;

    const int prow = ((c >> 2) << 3) + (c & 3);   // permuted key row (octet low)

    int kbeg = s * seg_len, kend = kbeg + seg_len;
    for (int kb = kbeg; kb < kend; kb += 32) {
        __syncthreads();   // lockstep the 4 waves -> K/V tile shared via L1

        const size_t k0 = ((size_t)(kb + prow)) * CH + g * 8;
        const size_t k1 = k0 + 4 * CH;
        bf16x8 kh00 = *(const bf16x8*)(Kbh + k0);
        bf16x8 kh01 = *(const bf16x8*)(Kbh + k0 + 32);
        bf16x8 kl00 = *(const bf16x8*)(Kbl + k0);
        bf16x8 kl01 = *(const bf16x8*)(Kbl + k0 + 32);
        bf16x8 kh10 = *(const bf16x8*)(Kbh + k1);
        bf16x8 kh11 = *(const bf16x8*)(Kbh + k1 + 32);
        bf16x8 kl10 = *(const bf16x8*)(Kbl + k1);
        bf16x8 kl11 = *(const bf16x8*)(Kbl + k1 + 32);

        f32x4 s0 = {0,0,0,0}, s1 = {0,0,0,0};
        // 3-product hi/lo split: hh + lh + hl (~fp32-accurate scores)
        s0 = MFMA16(kh00, qbh[0], s0); s0 = MFMA16(kh01, qbh[1], s0);
        s0 = MFMA16(kl00, qbh[0], s0); s0 = MFMA16(kl01, qbh[1], s0);
        s0 = MFMA16(kh00, qbl[0], s0); s0 = MFMA16(kh01, qbl[1], s0);
        s1 = MFMA16(kh10, qbh[0], s1); s1 = MFMA16(kh11, qbh[1], s1);
        s1 = MFMA16(kl10, qbh[0], s1); s1 = MFMA16(kl11, qbh[1], s1);
        s1 = MFMA16(kh10, qbl[0], s1); s1 = MFMA16(kh11, qbl[1], s1);

        // local max over this lane's 8 keys (for the rare-trigger check)
        float pq = fmaxf(fmaxf(fmaxf(s0[0], s0[1]), fmaxf(s0[2], s0[3])),
                         fmaxf(fmaxf(s1[0], s1[1]), fmaxf(s1[2], s1[3])));
        if (__any(pq > mreg + 12.0f)) {        // defer-max (log2 units)
            pq = fmaxf(pq, __shfl_xor(pq, 16));
            pq = fmaxf(pq, __shfl_xor(pq, 32));  // per-query max, g-consistent
            float mn = fmaxf(mreg, pq);
            float sc = exp2f(mreg - mn);         // rescale for query c
            lreg *= sc;
            mreg = mn;
#pragma unroll
            for (int r = 0; r < 4; ++r) {        // o rows are queries g*4+r
                float scr = __shfl(sc, g * 4 + r);
                o0[r] *= scr; o1[r] *= scr; o2[r] *= scr; o3[r] *= scr;
            }
        }

        float p0[4], p1[4];
#pragma unroll
        for (int r = 0; r < 4; ++r) {
            p0[r] = exp2f(s0[r] - mreg);
            p1[r] = exp2f(s1[r] - mreg);
        }
        lreg += ((p0[0] + p0[1]) + (p0[2] + p0[3]))
              + ((p1[0] + p1[1]) + (p1[2] + p1[3]));

        // P -> PV A-fragment, fully in-lane (keys already in natural order)
        union { unsigned u[4]; bf16x8 v; } pa;
        pa.u[0] = cvtpk(p0[0], p0[1]);
        pa.u[1] = cvtpk(p0[2], p0[3]);
        pa.u[2] = cvtpk(p1[0], p1[1]);
        pa.u[3] = cvtpk(p1[2], p1[3]);

        const size_t vcol = (size_t)c * SEQ + kb + g * 8;   // Vt[d][l]
        bf16x8 vf0 = *(const bf16x8*)(Vb + vcol);
        bf16x8 vf1 = *(const bf16x8*)(Vb + (size_t)16 * SEQ + vcol);
        bf16x8 vf2 = *(const bf16x8*)(Vb + (size_t)32 * SEQ + vcol);
        bf16x8 vf3 = *(const bf16x8*)(Vb + (size_t)48 * SEQ + vcol);
        o0 = MFMA16(pa.v, vf0, o0);
        o1 = MFMA16(pa.v, vf1, o1);
        o2 = MFMA16(pa.v, vf2, o2);
        o3 = MFMA16(pa.v, vf3, o3);
    }

    // deferred l: cross-g reduce (query c)
    float lt = lreg;
    lt += __shfl_xor(lt, 16);
    lt += __shfl_xor(lt, 32);

    float* Ob = Opart + (size_t)s * ((size_t)BATCH * SEQ * CH) + ((size_t)b * SEQ + q0) * CH;
#pragma unroll
    for (int r = 0; r < 4; ++r) {
        int row = g * 4 + r;
        Ob[(size_t)row * CH +  0 + c] = o0[r];
        Ob[(size_t)row * CH + 16 + c] = o1[r];
        Ob[(size_t)row * CH + 32 + c] = o2[r];
        Ob[(size_t)row * CH + 48 + c] = o3[r];
    }
    if (g == 0) {
        int row = b * SEQ + q0 + c;
        Mp[s * (BATCH * SEQ) + row] = mreg;
        Lp[s * (BATCH * SEQ) + row] = lt;
    }
}

// ---------------------------------------------------------------------------
// K2b: combine split partials via log-sum-exp weighting (log2 units).
// ---------------------------------------------------------------------------
__global__ __launch_bounds__(256) void combine_kernel(
        const float* __restrict__ Opart, const float* __restrict__ Mp,
        const float* __restrict__ Lp, float* __restrict__ Obuf, int nsplit) {
    const int total = BATCH * SEQ * CH;
    for (int idx = blockIdx.x * 256 + threadIdx.x; idx < total; idx += gridDim.x * 256) {
        int row = idx >> 6;
        float M = -1e30f;
        for (int s2 = 0; s2 < nsplit; ++s2) M = fmaxf(M, Mp[s2 * (BATCH * SEQ) + row]);
        float num = 0.f, den = 0.f;
        for (int s2 = 0; s2 < nsplit; ++s2) {
            float w = exp2f(Mp[s2 * (BATCH * SEQ) + row] - M);
            den = fmaf(w, Lp[s2 * (BATCH * SEQ) + row], den);
            num = fmaf(w, Opart[(size_t)s2 * total + idx], num);
        }
        Obuf[idx] = num / den;
    }
}

// ---------------------------------------------------------------------------
// K3: final 1x1 conv (fp32 VALU; only 0.5 GFLOP)  (R1-passing)
// ---------------------------------------------------------------------------
__global__ __launch_bounds__(256) void out_conv_kernel(
        const float* __restrict__ O, const float* __restrict__ wo,
        const float* __restrict__ bo, float* __restrict__ out) {
    int rowblk = blockIdx.x;
    int b  = rowblk / (SEQ / 64);
    int l0 = (rowblk % (SEQ / 64)) * 64;
    __shared__ float Ws[CH][65];
    __shared__ float xs[64][CH];
    int tid = threadIdx.x;
    for (int idx = tid; idx < CH * CH; idx += 256) {
        int i = idx >> 6, cc = idx & 63;
        Ws[cc][i] = wo[idx];
    }
    for (int idx = tid; idx < 64 * CH; idx += 256) {
        int rr = idx >> 6, cc = idx & 63;
        xs[rr][cc] = O[((size_t)b * SEQ + l0 + rr) * CH + cc];
    }
    __syncthreads();
    int wave = tid >> 6, lane = tid & 63;
    int lr0 = wave * 16;
    float acc[16];
    float bias = bo[lane];
#pragma unroll
    for (int r = 0; r < 16; ++r) acc[r] = bias;
    for (int i = 0; i < CH; i += 4) {
        float w0 = Ws[lane][i], w1 = Ws[lane][i + 1], w2 = Ws[lane][i + 2], w3 = Ws[lane][i + 3];
#pragma unroll
        for (int r = 0; r < 16; ++r) {
            const float* xr = &xs[lr0 + r][i];
            acc[r] = fmaf(xr[0], w0, acc[r]);
            acc[r] = fmaf(xr[1], w1, acc[r]);
            acc[r] = fmaf(xr[2], w2, acc[r]);
            acc[r] = fmaf(xr[3], w3, acc[r]);
        }
    }
    float* ob = out + ((size_t)b * SEQ + l0 + lr0) * CH + lane;
#pragma unroll
    for (int r = 0; r < 16; ++r) ob[(size_t)r * CH] = acc[r];
}

// ---------------------------------------------------------------------------
extern "C" void kernel_launch(void* const* d_in, const int* in_sizes, int n_in,
                              void* d_out, int out_size, void* d_ws, size_t ws_size,
                              hipStream_t stream) {
    (void)in_sizes; (void)n_in; (void)out_size;
    const float* Q  = (const float*)d_in[0];
    const float* K  = (const float*)d_in[1];
    const float* V  = (const float*)d_in[2];
    const float* wq = (const float*)d_in[3];
    const float* bq = (const float*)d_in[4];
    const float* wk = (const float*)d_in[5];
    const float* bk = (const float*)d_in[6];
    const float* wv = (const float*)d_in[7];
    const float* bv = (const float*)d_in[8];
    const float* wd = (const float*)d_in[9];
    const float* bd = (const float*)d_in[10];
    const float* wo = (const float*)d_in[11];
    const float* bo = (const float*)d_in[12];
    float* out = (float*)d_out;

    const size_t NEL = (size_t)BATCH * SEQ * CH;   // 2097152
    char* ws = (char*)d_ws;
    unsigned short* Wth = (unsigned short*)(ws);                 // 73728 B
    unsigned short* Wtl = (unsigned short*)(ws + 73728);         // 73728 B
    float* bbp = (float*)(ws + 147456);                          // 2304 B
    unsigned short* Qh = (unsigned short*)(ws + 163840);
    unsigned short* Ql = Qh + NEL;
    unsigned short* Kh = Ql + NEL;
    unsigned short* Kl = Kh + NEL;
    unsigned short* Vt = Kl + NEL;                               // ends at 21135360

    const size_t NEED4 = 22183936 + 5u * 8388608;   // NS=4 (proven fit in R2)
    const size_t NEED2 = 22183936 + 3u * 8388608;
    int NS = (ws_size >= NEED4) ? 4 : (ws_size >= NEED2) ? 2 : 1;

    float* Mp    = (float*)(ws + 21135360);
    float* Lp    = (float*)(ws + 21659648);
    float* Opart = (float*)(ws + 22183936);
    float* Obuf  = (float*)(ws + 22183936 + (size_t)NS * 8388608);

    combine_w_kernel<<<9, 256, 0, stream>>>(wq, bq, wk, bk, wv, bv, wd, Wth, Wtl, bbp);
    conv_mfma_kernel<<<dim3(512, 3), 256, 0, stream>>>(
        Q, K, V, Wth, Wtl, bbp, bd, Qh, Ql, Kh, Kl, Vt);
    attn_kernel<<<512 * NS, 256, 0, stream>>>(
        Qh, Ql, Kh, Kl, Vt, Opart, Mp, Lp, SEQ / NS);
    combine_kernel<<<2048, 256, 0, stream>>>(Opart, Mp, Lp, Obuf, NS);
    out_conv_kernel<<<BATCH * SEQ / 64, 256, 0, stream>>>(Obuf, wo, bo, out);
}

// Round 6
// 366.407 us; speedup vs baseline: 1.5594x; 1.5594x over previous
//
#include <hip/hip_runtime.h>

#define BATCH 8
#define SEQ   4096
#define CH    64
#define KDIM  192   // 3 taps x 64 channels
#define LOG2E 1.44269504f

typedef __attribute__((ext_vector_type(8))) short bf16x8;    // 8 bf16 in 4 VGPRs
typedef __attribute__((ext_vector_type(4))) float f32x4;

#define MFMA16(a, b, c) __builtin_amdgcn_mfma_f32_16x16x32_bf16(a, b, c, 0, 0, 0)

__device__ __forceinline__ unsigned short f2bf(float f) {
    union { float f; unsigned int u; } v; v.f = f;
    unsigned int r = v.u + 0x7fffu + ((v.u >> 16) & 1u);   // RNE
    return (unsigned short)(r >> 16);
}
__device__ __forceinline__ float bf2f(unsigned short h) {
    union { float f; unsigned int u; } v; v.u = ((unsigned int)h) << 16;
    return v.f;
}
// pack two f32 -> one u32 of 2 bf16 (lo = first arg)
__device__ __forceinline__ unsigned cvtpk(float lo, float hi) {
    unsigned r;
    asm volatile("v_cvt_pk_bf16_f32 %0, %1, %2" : "=v"(r) : "v"(lo), "v"(hi));
    return r;
}

// ---------------------------------------------------------------------------
// K0: fold 1x1 convs into the shared 3-tap conv (R2/R5-passing).
// ---------------------------------------------------------------------------
__global__ void combine_w_kernel(const float* __restrict__ wq, const float* __restrict__ bq,
                                 const float* __restrict__ wk, const float* __restrict__ bk,
                                 const float* __restrict__ wv, const float* __restrict__ bv,
                                 const float* __restrict__ wd,
                                 unsigned short* __restrict__ Wth, unsigned short* __restrict__ Wtl,
                                 float* __restrict__ bbp) {
    int T = blockIdx.x / 3, t = blockIdx.x % 3;
    const float* w1 = (T == 0) ? wq : (T == 1) ? wk : wv;
    const float* b1 = (T == 0) ? bq : (T == 1) ? bk : bv;
    const float* wdt = wd + t * CH * CH;
    for (int idx = threadIdx.x; idx < CH * CH; idx += blockDim.x) {
        int i = idx >> 6, c = idx & 63;
        float acc = 0.f;
        for (int m = 0; m < CH; ++m) acc = fmaf(w1[i * CH + m], wdt[m * CH + c], acc);
        unsigned short h = f2bf(acc);
        size_t o = ((size_t)(T * CH + c)) * KDIM + t * CH + i;
        Wth[o] = h;
        Wtl[o] = f2bf(acc - bf2f(h));
    }
    if (threadIdx.x < CH) {
        int c = threadIdx.x;
        float acc = 0.f;
        for (int m = 0; m < CH; ++m) acc = fmaf(b1[m], wdt[m * CH + c], acc);
        bbp[(T * 3 + t) * CH + c] = acc;
    }
}

// ---------------------------------------------------------------------------
// K1: MFMA conv (R2/R5-passing). Q scaled by log2(e) so attn uses exp2.
// ---------------------------------------------------------------------------
__global__ __launch_bounds__(256) void conv_mfma_kernel(
        const float* __restrict__ Q, const float* __restrict__ K, const float* __restrict__ V,
        const unsigned short* __restrict__ Wth, const unsigned short* __restrict__ Wtl,
        const float* __restrict__ bbp, const float* __restrict__ bd,
        unsigned short* __restrict__ Qh, unsigned short* __restrict__ Ql,
        unsigned short* __restrict__ Kh, unsigned short* __restrict__ Kl,
        unsigned short* __restrict__ Vt) {
    int T = blockIdx.y;
    const float* X = (T == 0) ? Q : (T == 1) ? K : V;
    int rowblk = blockIdx.x;          // 0..511
    int b  = rowblk >> 6;
    int l0 = (rowblk & 63) << 6;

    __shared__ unsigned short xh[66][64];
    __shared__ unsigned short xl[66][64];

    int tid = threadIdx.x;
    for (int q4 = tid; q4 < 66 * 16; q4 += 256) {
        int row = q4 >> 4, i = (q4 & 15) << 2;
        int gl = l0 + row - 1;
        float4 v = make_float4(0.f, 0.f, 0.f, 0.f);
        if (gl >= 0 && gl < SEQ) v = *(const float4*)(X + ((size_t)b * SEQ + gl) * CH + i);
        unsigned short h0 = f2bf(v.x), h1 = f2bf(v.y), h2 = f2bf(v.z), h3 = f2bf(v.w);
        unsigned short e0 = f2bf(v.x - bf2f(h0)), e1 = f2bf(v.y - bf2f(h1));
        unsigned short e2 = f2bf(v.z - bf2f(h2)), e3 = f2bf(v.w - bf2f(h3));
        int sw = i ^ ((row & 7) << 3);
        uint2 hp = { (unsigned)h0 | ((unsigned)h1 << 16), (unsigned)h2 | ((unsigned)h3 << 16) };
        uint2 lp = { (unsigned)e0 | ((unsigned)e1 << 16), (unsigned)e2 | ((unsigned)e3 << 16) };
        *(uint2*)&xh[row][sw] = hp;
        *(uint2*)&xl[row][sw] = lp;
    }
    __syncthreads();

    int wave = tid >> 6, lane = tid & 63;
    int g = lane >> 4, cc = lane & 15;
    int wrow0 = wave << 4;

    bf16x8 ah[6], al[6];
#pragma unroll
    for (int kk = 0; kk < 6; ++kk) {
        int t = kk >> 1;
        int u = wrow0 + cc + t;
        int blk = (((kk & 1) * 4 + g) ^ (u & 7));
        ah[kk] = *(const bf16x8*)&xh[u][blk << 3];
        al[kk] = *(const bf16x8*)&xl[u][blk << 3];
    }

    for (int nt = 0; nt < 4; ++nt) {
        int col = nt * 16 + cc;
        const unsigned short* wbh = Wth + ((size_t)(T * CH + col)) * KDIM;
        const unsigned short* wbl = Wtl + ((size_t)(T * CH + col)) * KDIM;
        f32x4 acc = {0.f, 0.f, 0.f, 0.f};
#pragma unroll
        for (int kk = 0; kk < 6; ++kk) {
            bf16x8 bh = *(const bf16x8*)(wbh + kk * 32 + g * 8);
            bf16x8 bl = *(const bf16x8*)(wbl + kk * 32 + g * 8);
            acc = MFMA16(ah[kk], bh, acc);
            acc = MFMA16(al[kk], bh, acc);
            acc = MFMA16(ah[kk], bl, acc);
        }
        float bias = bd[col] + bbp[(T * 3 + 0) * CH + col] + bbp[(T * 3 + 1) * CH + col]
                   + bbp[(T * 3 + 2) * CH + col];
#pragma unroll
        for (int r = 0; r < 4; ++r) {
            int gl = l0 + wrow0 + g * 4 + r;
            float v = acc[r] + bias;
            if (gl == 0)       v -= bbp[(T * 3 + 0) * CH + col];
            if (gl == SEQ - 1) v -= bbp[(T * 3 + 2) * CH + col];
            if (T == 0) {
                float vq = v * LOG2E;
                unsigned short h = f2bf(vq);
                Qh[((size_t)b * SEQ + gl) * CH + col] = h;
                Ql[((size_t)b * SEQ + gl) * CH + col] = f2bf(vq - bf2f(h));
            } else if (T == 1) {
                unsigned short h = f2bf(v);
                Kh[((size_t)b * SEQ + gl) * CH + col] = h;
                Kl[((size_t)b * SEQ + gl) * CH + col] = f2bf(v - bf2f(h));
            } else {
                Vt[((size_t)b * CH + col) * SEQ + gl] = f2bf(v);
            }
        }
    }
}

// ---------------------------------------------------------------------------
// K2: flash attention — R5's verified math (permuted key rows, in-lane P),
// restructured: no barriers, K register double-buffer prefetched 1 tile
// ahead, V issued before K-prefetch (PV waits vmcnt(8), never a drain),
// 32 q-rows per wave (two 16-q sub-tiles sharing K/V regs).
// grid: 256*NS blocks (b = bid&7 XCD-pinned), 4 waves x 32 q = 128 q/block.
// ---------------------------------------------------------------------------
#define LOADK(h0,h1,h2,h3,e0,e1,e2,e3, kb_) do {                                   \
    const size_t k0_ = ((size_t)((kb_) + prow)) * CH + (size_t)(g * 8);            \
    h0 = *(const bf16x8*)(Kbh + k0_);          h1 = *(const bf16x8*)(Kbh + k0_ + 32); \
    h2 = *(const bf16x8*)(Kbh + k0_ + 4*CH);   h3 = *(const bf16x8*)(Kbh + k0_ + 4*CH + 32); \
    e0 = *(const bf16x8*)(Kbl + k0_);          e1 = *(const bf16x8*)(Kbl + k0_ + 32); \
    e2 = *(const bf16x8*)(Kbl + k0_ + 4*CH);   e3 = *(const bf16x8*)(Kbl + k0_ + 4*CH + 32); \
} while (0)

#define PREV(kb_) do {                                                             \
    const size_t v0_ = (size_t)c * SEQ + (kb_) + g * 8;                            \
    vf0 = *(const bf16x8*)(Vb + v0_);                                              \
    vf1 = *(const bf16x8*)(Vb + (size_t)16 * SEQ + v0_);                           \
    vf2 = *(const bf16x8*)(Vb + (size_t)32 * SEQ + v0_);                           \
    vf3 = *(const bf16x8*)(Vb + (size_t)48 * SEQ + v0_);                           \
} while (0)

#define SOFTMAX_SUB(s0_, s1_, m_, l_, oA, oB, oC, oD, pa_) do {                    \
    float pq_ = fmaxf(fmaxf(fmaxf(s0_[0], s0_[1]), fmaxf(s0_[2], s0_[3])),         \
                      fmaxf(fmaxf(s1_[0], s1_[1]), fmaxf(s1_[2], s1_[3])));        \
    if (__any(pq_ > m_ + 12.0f)) {                                                 \
        pq_ = fmaxf(pq_, __shfl_xor(pq_, 16));                                     \
        pq_ = fmaxf(pq_, __shfl_xor(pq_, 32));                                     \
        float mn_ = fmaxf(m_, pq_);                                                \
        float sc_ = exp2f(m_ - mn_);                                               \
        l_ *= sc_; m_ = mn_;                                                       \
        _Pragma("unroll") for (int r_ = 0; r_ < 4; ++r_) {                         \
            float f_ = __shfl(sc_, g * 4 + r_);                                    \
            oA[r_] *= f_; oB[r_] *= f_; oC[r_] *= f_; oD[r_] *= f_;                \
        }                                                                          \
    }                                                                              \
    float p0_[4], p1_[4];                                                          \
    _Pragma("unroll") for (int r_ = 0; r_ < 4; ++r_) {                             \
        p0_[r_] = exp2f(s0_[r_] - m_);                                             \
        p1_[r_] = exp2f(s1_[r_] - m_);                                             \
    }                                                                              \
    l_ += ((p0_[0] + p0_[1]) + (p0_[2] + p0_[3]))                                  \
        + ((p1_[0] + p1_[1]) + (p1_[2] + p1_[3]));                                 \
    pa_.u[0] = cvtpk(p0_[0], p0_[1]); pa_.u[1] = cvtpk(p0_[2], p0_[3]);            \
    pa_.u[2] = cvtpk(p1_[0], p1_[1]); pa_.u[3] = cvtpk(p1_[2], p1_[3]);            \
} while (0)

#define COMPUTE(h0,h1,h2,h3,e0,e1,e2,e3) do {                                      \
    f32x4 s00 = {0,0,0,0}, s01 = {0,0,0,0}, s10 = {0,0,0,0}, s11 = {0,0,0,0};      \
    s00 = MFMA16(h0, qh0a, s00); s10 = MFMA16(h0, qh1a, s10);                      \
    s01 = MFMA16(h2, qh0a, s01); s11 = MFMA16(h2, qh1a, s11);                      \
    s00 = MFMA16(h1, qh0b, s00); s10 = MFMA16(h1, qh1b, s10);                      \
    s01 = MFMA16(h3, qh0b, s01); s11 = MFMA16(h3, qh1b, s11);                      \
    s00 = MFMA16(e0, qh0a, s00); s10 = MFMA16(e0, qh1a, s10);                      \
    s01 = MFMA16(e2, qh0a, s01); s11 = MFMA16(e2, qh1a, s11);                      \
    s00 = MFMA16(e1, qh0b, s00); s10 = MFMA16(e1, qh1b, s10);                      \
    s01 = MFMA16(e3, qh0b, s01); s11 = MFMA16(e3, qh1b, s11);                      \
    s00 = MFMA16(h0, ql0a, s00); s10 = MFMA16(h0, ql1a, s10);                      \
    s01 = MFMA16(h2, ql0a, s01); s11 = MFMA16(h2, ql1a, s11);                      \
    s00 = MFMA16(h1, ql0b, s00); s10 = MFMA16(h1, ql1b, s10);                      \
    s01 = MFMA16(h3, ql0b, s01); s11 = MFMA16(h3, ql1b, s11);                      \
    union { unsigned u[4]; bf16x8 v; } pa0_, pa1_;                                 \
    SOFTMAX_SUB(s00, s01, m0, l0, o00, o01, o02, o03, pa0_);                       \
    SOFTMAX_SUB(s10, s11, m1, l1, o10, o11, o12, o13, pa1_);                       \
    o00 = MFMA16(pa0_.v, vf0, o00); o01 = MFMA16(pa0_.v, vf1, o01);                \
    o02 = MFMA16(pa0_.v, vf2, o02); o03 = MFMA16(pa0_.v, vf3, o03);                \
    o10 = MFMA16(pa1_.v, vf0, o10); o11 = MFMA16(pa1_.v, vf1, o11);                \
    o12 = MFMA16(pa1_.v, vf2, o12); o13 = MFMA16(pa1_.v, vf3, o13);                \
} while (0)

__global__ __launch_bounds__(256) void attn_kernel(
        const unsigned short* __restrict__ Qh, const unsigned short* __restrict__ Ql,
        const unsigned short* __restrict__ Kh, const unsigned short* __restrict__ Kl,
        const unsigned short* __restrict__ Vt,
        float* __restrict__ Opart, float* __restrict__ Mp, float* __restrict__ Lp,
        int seg_len) {
    int bid  = blockIdx.x;
    int s    = bid >> 8;
    int b    = bid & 7;
    int qt   = (bid >> 3) & 31;
    int wave = threadIdx.x >> 6;
    int lane = threadIdx.x & 63;
    int c = lane & 15, g = lane >> 4;
    int q0 = qt * 128 + wave * 32;          // 32 q-rows per wave

    // Q fragments for both 16-q sub-tiles (col = query c, k = ch*32 + g*8 + i)
    bf16x8 qh0a, qh0b, ql0a, ql0b, qh1a, qh1b, ql1a, ql1b;
    {
        const size_t qo0 = ((size_t)b * SEQ + q0 + c) * CH + g * 8;
        const size_t qo1 = qo0 + (size_t)16 * CH;
        qh0a = *(const bf16x8*)(Qh + qo0);  qh0b = *(const bf16x8*)(Qh + qo0 + 32);
        ql0a = *(const bf16x8*)(Ql + qo0);  ql0b = *(const bf16x8*)(Ql + qo0 + 32);
        qh1a = *(const bf16x8*)(Qh + qo1);  qh1b = *(const bf16x8*)(Qh + qo1 + 32);
        ql1a = *(const bf16x8*)(Ql + qo1);  ql1b = *(const bf16x8*)(Ql + qo1 + 32);
    }

    f32x4 o00 = {0,0,0,0}, o01 = {0,0,0,0}, o02 = {0,0,0,0}, o03 = {0,0,0,0};
    f32x4 o10 = {0,0,0,0}, o11 = {0,0,0,0}, o12 = {0,0,0,0}, o13 = {0,0,0,0};
    float m0 = -1e30f, m1 = -1e30f, l0 = 0.f, l1 = 0.f;

    const unsigned short* Kbh = Kh + (size_t)b * SEQ * CH;
    const unsigned short* Kbl = Kl + (size_t)b * SEQ * CH;
    const unsigned short* Vb  = Vt + (size_t)b * CH * SEQ;

    const int prow = ((c >> 2) << 3) + (c & 3);   // permuted key row (octet low)

    bf16x8 Ah0, Ah1, Ah2, Ah3, Ae0, Ae1, Ae2, Ae3;   // K double buffer
    bf16x8 Bh0, Bh1, Bh2, Bh3, Be0, Be1, Be2, Be3;
    bf16x8 vf0, vf1, vf2, vf3;

    int kbeg = s * seg_len;
    int nt2  = seg_len >> 6;                // pairs of 32-key tiles
    int kb   = kbeg;

    LOADK(Ah0,Ah1,Ah2,Ah3,Ae0,Ae1,Ae2,Ae3, kbeg);
    for (int it = 0; it < nt2 - 1; ++it, kb += 64) {
        PREV(kb);                                        // V for tile kb (oldest pending after A)
        LOADK(Bh0,Bh1,Bh2,Bh3,Be0,Be1,Be2,Be3, kb + 32); // prefetch next tile
        COMPUTE(Ah0,Ah1,Ah2,Ah3,Ae0,Ae1,Ae2,Ae3);        // QK waits on A (done); PV waits vmcnt(8)
        PREV(kb + 32);
        LOADK(Ah0,Ah1,Ah2,Ah3,Ae0,Ae1,Ae2,Ae3, kb + 64);
        COMPUTE(Bh0,Bh1,Bh2,Bh3,Be0,Be1,Be2,Be3);
    }
    PREV(kb);
    LOADK(Bh0,Bh1,Bh2,Bh3,Be0,Be1,Be2,Be3, kb + 32);
    COMPUTE(Ah0,Ah1,Ah2,Ah3,Ae0,Ae1,Ae2,Ae3);
    PREV(kb + 32);
    COMPUTE(Bh0,Bh1,Bh2,Bh3,Be0,Be1,Be2,Be3);

    // deferred cross-g l reduction (per query c)
    l0 += __shfl_xor(l0, 16);  l0 += __shfl_xor(l0, 32);
    l1 += __shfl_xor(l1, 16);  l1 += __shfl_xor(l1, 32);

    float* Ob = Opart + (size_t)s * ((size_t)BATCH * SEQ * CH) + ((size_t)b * SEQ + q0) * CH;
#pragma unroll
    for (int r = 0; r < 4; ++r) {
        int row = g * 4 + r;
        Ob[(size_t)row * CH +  0 + c] = o00[r];
        Ob[(size_t)row * CH + 16 + c] = o01[r];
        Ob[(size_t)row * CH + 32 + c] = o02[r];
        Ob[(size_t)row * CH + 48 + c] = o03[r];
        int row1 = row + 16;
        Ob[(size_t)row1 * CH +  0 + c] = o10[r];
        Ob[(size_t)row1 * CH + 16 + c] = o11[r];
        Ob[(size_t)row1 * CH + 32 + c] = o12[r];
        Ob[(size_t)row1 * CH + 48 + c] = o13[r];
    }
    if (g == 0) {
        int row = b * SEQ + q0 + c;
        Mp[s * (BATCH * SEQ) + row]      = m0;
        Lp[s * (BATCH * SEQ) + row]      = l0;
        Mp[s * (BATCH * SEQ) + row + 16] = m1;
        Lp[s * (BATCH * SEQ) + row + 16] = l1;
    }
}

// ---------------------------------------------------------------------------
// K2b: combine split partials via log-sum-exp weighting (log2 units).
// ---------------------------------------------------------------------------
__global__ __launch_bounds__(256) void combine_kernel(
        const float* __restrict__ Opart, const float* __restrict__ Mp,
        const float* __restrict__ Lp, float* __restrict__ Obuf, int nsplit) {
    const int total = BATCH * SEQ * CH;
    for (int idx = blockIdx.x * 256 + threadIdx.x; idx < total; idx += gridDim.x * 256) {
        int row = idx >> 6;
        float M = -1e30f;
        for (int s2 = 0; s2 < nsplit; ++s2) M = fmaxf(M, Mp[s2 * (BATCH * SEQ) + row]);
        float num = 0.f, den = 0.f;
        for (int s2 = 0; s2 < nsplit; ++s2) {
            float w = exp2f(Mp[s2 * (BATCH * SEQ) + row] - M);
            den = fmaf(w, Lp[s2 * (BATCH * SEQ) + row], den);
            num = fmaf(w, Opart[(size_t)s2 * total + idx], num);
        }
        Obuf[idx] = num / den;
    }
}

// ---------------------------------------------------------------------------
// K3: final 1x1 conv (fp32 VALU; only 0.5 GFLOP)
// ---------------------------------------------------------------------------
__global__ __launch_bounds__(256) void out_conv_kernel(
        const float* __restrict__ O, const float* __restrict__ wo,
        const float* __restrict__ bo, float* __restrict__ out) {
    int rowblk = blockIdx.x;
    int b  = rowblk / (SEQ / 64);
    int l0 = (rowblk % (SEQ / 64)) * 64;
    __shared__ float Ws[CH][65];
    __shared__ float xs[64][CH];
    int tid = threadIdx.x;
    for (int idx = tid; idx < CH * CH; idx += 256) {
        int i = idx >> 6, cc = idx & 63;
        Ws[cc][i] = wo[idx];
    }
    for (int idx = tid; idx < 64 * CH; idx += 256) {
        int rr = idx >> 6, cc = idx & 63;
        xs[rr][cc] = O[((size_t)b * SEQ + l0 + rr) * CH + cc];
    }
    __syncthreads();
    int wave = tid >> 6, lane = tid & 63;
    int lr0 = wave * 16;
    float acc[16];
    float bias = bo[lane];
#pragma unroll
    for (int r = 0; r < 16; ++r) acc[r] = bias;
    for (int i = 0; i < CH; i += 4) {
        float w0 = Ws[lane][i], w1 = Ws[lane][i + 1], w2 = Ws[lane][i + 2], w3 = Ws[lane][i + 3];
#pragma unroll
        for (int r = 0; r < 16; ++r) {
            const float* xr = &xs[lr0 + r][i];
            acc[r] = fmaf(xr[0], w0, acc[r]);
            acc[r] = fmaf(xr[1], w1, acc[r]);
            acc[r] = fmaf(xr[2], w2, acc[r]);
            acc[r] = fmaf(xr[3], w3, acc[r]);
        }
    }
    float* ob = out + ((size_t)b * SEQ + l0 + lr0) * CH + lane;
#pragma unroll
    for (int r = 0; r < 16; ++r) ob[(size_t)r * CH] = acc[r];
}

// ---------------------------------------------------------------------------
extern "C" void kernel_launch(void* const* d_in, const int* in_sizes, int n_in,
                              void* d_out, int out_size, void* d_ws, size_t ws_size,
                              hipStream_t stream) {
    (void)in_sizes; (void)n_in; (void)out_size;
    const float* Q  = (const float*)d_in[0];
    const float* K  = (const float*)d_in[1];
    const float* V  = (const float*)d_in[2];
    const float* wq = (const float*)d_in[3];
    const float* bq = (const float*)d_in[4];
    const float* wk = (const float*)d_in[5];
    const float* bk = (const float*)d_in[6];
    const float* wv = (const float*)d_in[7];
    const float* bv = (const float*)d_in[8];
    const float* wd = (const float*)d_in[9];
    const float* bd = (const float*)d_in[10];
    const float* wo = (const float*)d_in[11];
    const float* bo = (const float*)d_in[12];
    float* out = (float*)d_out;

    const size_t NEL = (size_t)BATCH * SEQ * CH;   // 2097152
    char* ws = (char*)d_ws;
    unsigned short* Wth = (unsigned short*)(ws);                 // 73728 B
    unsigned short* Wtl = (unsigned short*)(ws + 73728);         // 73728 B
    float* bbp = (float*)(ws + 147456);                          // 2304 B
    unsigned short* Qh = (unsigned short*)(ws + 163840);
    unsigned short* Ql = Qh + NEL;
    unsigned short* Kh = Ql + NEL;
    unsigned short* Kl = Kh + NEL;
    unsigned short* Vt = Kl + NEL;                               // ends at 21135360

    const size_t NEED4 = 22183936 + 5u * 8388608;   // NS=4 (proven fit)
    const size_t NEED2 = 22183936 + 3u * 8388608;
    int NS = (ws_size >= NEED4) ? 4 : (ws_size >= NEED2) ? 2 : 1;

    float* Mp    = (float*)(ws + 21135360);
    float* Lp    = (float*)(ws + 21659648);
    float* Opart = (float*)(ws + 22183936);
    float* Obuf  = (float*)(ws + 22183936 + (size_t)NS * 8388608);

    combine_w_kernel<<<9, 256, 0, stream>>>(wq, bq, wk, bk, wv, bv, wd, Wth, Wtl, bbp);
    conv_mfma_kernel<<<dim3(512, 3), 256, 0, stream>>>(
        Q, K, V, Wth, Wtl, bbp, bd, Qh, Ql, Kh, Kl, Vt);
    attn_kernel<<<256 * NS, 256, 0, stream>>>(
        Qh, Ql, Kh, Kl, Vt, Opart, Mp, Lp, SEQ / NS);
    combine_kernel<<<2048, 256, 0, stream>>>(Opart, Mp, Lp, Obuf, NS);
    out_conv_kernel<<<BATCH * SEQ / 64, 256, 0, stream>>>(Obuf, wo, bo, out);
}

// Round 7
// 275.872 us; speedup vs baseline: 2.0711x; 1.3282x over previous
//
#include <hip/hip_runtime.h>

#define BATCH 8
#define SEQ   4096
#define CH    64
#define KDIM  192   // 3 taps x 64 channels
#define LOG2E 1.44269504f

typedef __attribute__((ext_vector_type(8))) short bf16x8;    // 8 bf16 in 4 VGPRs
typedef __attribute__((ext_vector_type(4))) float f32x4;

#define MFMA16(a, b, c) __builtin_amdgcn_mfma_f32_16x16x32_bf16(a, b, c, 0, 0, 0)

__device__ __forceinline__ unsigned short f2bf(float f) {
    union { float f; unsigned int u; } v; v.f = f;
    unsigned int r = v.u + 0x7fffu + ((v.u >> 16) & 1u);   // RNE
    return (unsigned short)(r >> 16);
}
__device__ __forceinline__ float bf2f(unsigned short h) {
    union { float f; unsigned int u; } v; v.u = ((unsigned int)h) << 16;
    return v.f;
}
// pack two f32 -> one u32 of 2 bf16 (first arg -> low 16)
__device__ __forceinline__ unsigned cvtpk(float lo, float hi) {
    unsigned r;
    asm volatile("v_cvt_pk_bf16_f32 %0, %1, %2" : "=v"(r) : "v"(lo), "v"(hi));
    return r;
}

// ---------------------------------------------------------------------------
// K0: fold 1x1 convs into the shared 3-tap conv; emit transposed hi/lo
// weights. Block 9 prepares transposed hi/lo wo for the fused epilogue.
// grid: 10 blocks, 256 threads.
// ---------------------------------------------------------------------------
__global__ void combine_w_kernel(const float* __restrict__ wq, const float* __restrict__ bq,
                                 const float* __restrict__ wk, const float* __restrict__ bk,
                                 const float* __restrict__ wv, const float* __restrict__ bv,
                                 const float* __restrict__ wd, const float* __restrict__ wo,
                                 unsigned short* __restrict__ Wth, unsigned short* __restrict__ Wtl,
                                 float* __restrict__ bbp,
                                 unsigned short* __restrict__ Woth, unsigned short* __restrict__ Wotl) {
    if (blockIdx.x == 9) {
        for (int idx = threadIdx.x; idx < CH * CH; idx += blockDim.x) {
            int i = idx >> 6, c = idx & 63;
            float w = wo[i * CH + c];
            unsigned short h = f2bf(w);
            Woth[c * CH + i] = h;
            Wotl[c * CH + i] = f2bf(w - bf2f(h));
        }
        return;
    }
    int T = blockIdx.x / 3, t = blockIdx.x % 3;
    const float* w1 = (T == 0) ? wq : (T == 1) ? wk : wv;
    const float* b1 = (T == 0) ? bq : (T == 1) ? bk : bv;
    const float* wdt = wd + t * CH * CH;
    for (int idx = threadIdx.x; idx < CH * CH; idx += blockDim.x) {
        int i = idx >> 6, c = idx & 63;
        float acc = 0.f;
        for (int m = 0; m < CH; ++m) acc = fmaf(w1[i * CH + m], wdt[m * CH + c], acc);
        unsigned short h = f2bf(acc);
        size_t o = ((size_t)(T * CH + c)) * KDIM + t * CH + i;
        Wth[o] = h;
        Wtl[o] = f2bf(acc - bf2f(h));
    }
    if (threadIdx.x < CH) {
        int c = threadIdx.x;
        float acc = 0.f;
        for (int m = 0; m < CH; ++m) acc = fmaf(b1[m], wdt[m * CH + c], acc);
        bbp[(T * 3 + t) * CH + c] = acc;
    }
}

// ---------------------------------------------------------------------------
// K1: MFMA conv. Q scaled by log2(e) so attn uses exp2. Staging and output
// conversion use cvt_pk_bf16 (hi/lo split is self-correcting under any
// rounding of the hi part). Vt written as packed uint2 (4 bf16/lane).
// ---------------------------------------------------------------------------
__global__ __launch_bounds__(256) void conv_mfma_kernel(
        const float* __restrict__ Q, const float* __restrict__ K, const float* __restrict__ V,
        const unsigned short* __restrict__ Wth, const unsigned short* __restrict__ Wtl,
        const float* __restrict__ bbp, const float* __restrict__ bd,
        unsigned short* __restrict__ Qh, unsigned short* __restrict__ Ql,
        unsigned short* __restrict__ Kh, unsigned short* __restrict__ Kl,
        unsigned short* __restrict__ Vt) {
    int T = blockIdx.y;
    const float* X = (T == 0) ? Q : (T == 1) ? K : V;
    int rowblk = blockIdx.x;          // 0..511
    int b  = rowblk >> 6;
    int l0 = (rowblk & 63) << 6;

    __shared__ unsigned short xh[66][64];
    __shared__ unsigned short xl[66][64];

    int tid = threadIdx.x;
    for (int q4 = tid; q4 < 66 * 16; q4 += 256) {
        int row = q4 >> 4, i = (q4 & 15) << 2;
        int gl = l0 + row - 1;
        float4 v = make_float4(0.f, 0.f, 0.f, 0.f);
        if (gl >= 0 && gl < SEQ) v = *(const float4*)(X + ((size_t)b * SEQ + gl) * CH + i);
        unsigned hp0 = cvtpk(v.x, v.y), hp1 = cvtpk(v.z, v.w);
        float b0 = __uint_as_float(hp0 << 16), b1 = __uint_as_float(hp0 & 0xffff0000u);
        float b2 = __uint_as_float(hp1 << 16), b3 = __uint_as_float(hp1 & 0xffff0000u);
        unsigned lp0 = cvtpk(v.x - b0, v.y - b1), lp1 = cvtpk(v.z - b2, v.w - b3);
        int sw = i ^ ((row & 7) << 3);
        uint2 hp = { hp0, hp1 }, lp = { lp0, lp1 };
        *(uint2*)&xh[row][sw] = hp;
        *(uint2*)&xl[row][sw] = lp;
    }
    __syncthreads();

    int wave = tid >> 6, lane = tid & 63;
    int g = lane >> 4, cc = lane & 15;
    int wrow0 = wave << 4;

    bf16x8 ah[6], al[6];
#pragma unroll
    for (int kk = 0; kk < 6; ++kk) {
        int t = kk >> 1;
        int u = wrow0 + cc + t;
        int blk = (((kk & 1) * 4 + g) ^ (u & 7));
        ah[kk] = *(const bf16x8*)&xh[u][blk << 3];
        al[kk] = *(const bf16x8*)&xl[u][blk << 3];
    }

    for (int nt = 0; nt < 4; ++nt) {
        int col = nt * 16 + cc;
        const unsigned short* wbh = Wth + ((size_t)(T * CH + col)) * KDIM;
        const unsigned short* wbl = Wtl + ((size_t)(T * CH + col)) * KDIM;
        f32x4 acc = {0.f, 0.f, 0.f, 0.f};
#pragma unroll
        for (int kk = 0; kk < 6; ++kk) {
            bf16x8 bh = *(const bf16x8*)(wbh + kk * 32 + g * 8);
            bf16x8 bl = *(const bf16x8*)(wbl + kk * 32 + g * 8);
            acc = MFMA16(ah[kk], bh, acc);
            acc = MFMA16(al[kk], bh, acc);
            acc = MFMA16(ah[kk], bl, acc);
        }
        float bias = bd[col] + bbp[(T * 3 + 0) * CH + col] + bbp[(T * 3 + 1) * CH + col]
                   + bbp[(T * 3 + 2) * CH + col];
        float y[4];
        int gl0 = l0 + wrow0 + g * 4;
#pragma unroll
        for (int r = 0; r < 4; ++r) {
            int gl = gl0 + r;
            float v = acc[r] + bias;
            if (gl == 0)       v -= bbp[(T * 3 + 0) * CH + col];
            if (gl == SEQ - 1) v -= bbp[(T * 3 + 2) * CH + col];
            y[r] = (T == 0) ? v * LOG2E : v;
        }
        if (T == 2) {
            unsigned v01 = cvtpk(y[0], y[1]), v23 = cvtpk(y[2], y[3]);
            uint2 pv = { v01, v23 };
            *(uint2*)(Vt + ((size_t)b * CH + col) * SEQ + gl0) = pv;
        } else {
            unsigned short* H = (T == 0) ? Qh : Kh;
            unsigned short* L = (T == 0) ? Ql : Kl;
            size_t base = ((size_t)b * SEQ + gl0) * CH + col;
            unsigned h01 = cvtpk(y[0], y[1]);
            unsigned l01 = cvtpk(y[0] - __uint_as_float(h01 << 16),
                                 y[1] - __uint_as_float(h01 & 0xffff0000u));
            unsigned h23 = cvtpk(y[2], y[3]);
            unsigned l23 = cvtpk(y[2] - __uint_as_float(h23 << 16),
                                 y[3] - __uint_as_float(h23 & 0xffff0000u));
            H[base]          = (unsigned short)h01;
            H[base + CH]     = (unsigned short)(h01 >> 16);
            H[base + 2 * CH] = (unsigned short)h23;
            H[base + 3 * CH] = (unsigned short)(h23 >> 16);
            L[base]          = (unsigned short)l01;
            L[base + CH]     = (unsigned short)(l01 >> 16);
            L[base + 2 * CH] = (unsigned short)l23;
            L[base + 3 * CH] = (unsigned short)(l23 >> 16);
        }
    }
}

// ---------------------------------------------------------------------------
// K2: flash attention — R6's verified math, 64 q-rows/wave (4 sub-tiles
// sharing one K double-buffer + V regs) to halve L2/L3 K/V traffic again.
// grid: 128*NS blocks (b = bid&7 XCD-pinned), 4 waves x 64 q = 256 q/block.
// Opart/Mp/Lp stores are nontemporal (keep K/V stream in L2).
// ---------------------------------------------------------------------------
#define LOADK(H, E, kb_) do {                                                      \
    const size_t k0_ = ((size_t)((kb_) + prow)) * CH + (size_t)(g * 8);            \
    H[0] = *(const bf16x8*)(Kbh + k0_);          H[1] = *(const bf16x8*)(Kbh + k0_ + 32); \
    H[2] = *(const bf16x8*)(Kbh + k0_ + 4*CH);   H[3] = *(const bf16x8*)(Kbh + k0_ + 4*CH + 32); \
    E[0] = *(const bf16x8*)(Kbl + k0_);          E[1] = *(const bf16x8*)(Kbl + k0_ + 32); \
    E[2] = *(const bf16x8*)(Kbl + k0_ + 4*CH);   E[3] = *(const bf16x8*)(Kbl + k0_ + 4*CH + 32); \
} while (0)

#define PREV(kb_) do {                                                             \
    const size_t v0_ = (size_t)c * SEQ + (kb_) + g * 8;                            \
    vf0 = *(const bf16x8*)(Vb + v0_);                                              \
    vf1 = *(const bf16x8*)(Vb + (size_t)16 * SEQ + v0_);                           \
    vf2 = *(const bf16x8*)(Vb + (size_t)32 * SEQ + v0_);                           \
    vf3 = *(const bf16x8*)(Vb + (size_t)48 * SEQ + v0_);                           \
} while (0)

#define COMPUTE4(H, E) do {                                                        \
    _Pragma("unroll")                                                              \
    for (int sub = 0; sub < 4; ++sub) {                                            \
        f32x4 s0 = {0,0,0,0}, s1 = {0,0,0,0};                                      \
        s0 = MFMA16(H[0], qh[sub][0], s0); s0 = MFMA16(H[1], qh[sub][1], s0);      \
        s1 = MFMA16(H[2], qh[sub][0], s1); s1 = MFMA16(H[3], qh[sub][1], s1);      \
        s0 = MFMA16(E[0], qh[sub][0], s0); s0 = MFMA16(E[1], qh[sub][1], s0);      \
        s1 = MFMA16(E[2], qh[sub][0], s1); s1 = MFMA16(E[3], qh[sub][1], s1);      \
        s0 = MFMA16(H[0], ql[sub][0], s0); s0 = MFMA16(H[1], ql[sub][1], s0);      \
        s1 = MFMA16(H[2], ql[sub][0], s1); s1 = MFMA16(H[3], ql[sub][1], s1);      \
        float pq_ = fmaxf(fmaxf(fmaxf(s0[0], s0[1]), fmaxf(s0[2], s0[3])),         \
                          fmaxf(fmaxf(s1[0], s1[1]), fmaxf(s1[2], s1[3])));        \
        if (__any(pq_ > m[sub] + 12.0f)) {                                         \
            pq_ = fmaxf(pq_, __shfl_xor(pq_, 16));                                 \
            pq_ = fmaxf(pq_, __shfl_xor(pq_, 32));                                 \
            float mn_ = fmaxf(m[sub], pq_);                                        \
            float sc_ = exp2f(m[sub] - mn_);                                       \
            l[sub] *= sc_; m[sub] = mn_;                                           \
            _Pragma("unroll") for (int r_ = 0; r_ < 4; ++r_) {                     \
                float f_ = __shfl(sc_, g * 4 + r_);                                \
                o[sub][0][r_] *= f_; o[sub][1][r_] *= f_;                          \
                o[sub][2][r_] *= f_; o[sub][3][r_] *= f_;                          \
            }                                                                      \
        }                                                                          \
        float p0_[4], p1_[4];                                                      \
        _Pragma("unroll") for (int r_ = 0; r_ < 4; ++r_) {                         \
            p0_[r_] = exp2f(s0[r_] - m[sub]);                                      \
            p1_[r_] = exp2f(s1[r_] - m[sub]);                                      \
        }                                                                          \
        l[sub] += ((p0_[0] + p0_[1]) + (p0_[2] + p0_[3]))                          \
                + ((p1_[0] + p1_[1]) + (p1_[2] + p1_[3]));                         \
        union { unsigned u[4]; bf16x8 v; } pa_;                                    \
        pa_.u[0] = cvtpk(p0_[0], p0_[1]); pa_.u[1] = cvtpk(p0_[2], p0_[3]);        \
        pa_.u[2] = cvtpk(p1_[0], p1_[1]); pa_.u[3] = cvtpk(p1_[2], p1_[3]);        \
        o[sub][0] = MFMA16(pa_.v, vf0, o[sub][0]);                                 \
        o[sub][1] = MFMA16(pa_.v, vf1, o[sub][1]);                                 \
        o[sub][2] = MFMA16(pa_.v, vf2, o[sub][2]);                                 \
        o[sub][3] = MFMA16(pa_.v, vf3, o[sub][3]);                                 \
    }                                                                              \
} while (0)

__global__ __launch_bounds__(256, 2) void attn_kernel(
        const unsigned short* __restrict__ Qh, const unsigned short* __restrict__ Ql,
        const unsigned short* __restrict__ Kh, const unsigned short* __restrict__ Kl,
        const unsigned short* __restrict__ Vt,
        float* __restrict__ Opart, float* __restrict__ Mp, float* __restrict__ Lp,
        int seg_len) {
    int bid  = blockIdx.x;
    int s    = bid >> 7;
    int b    = bid & 7;
    int qt   = (bid >> 3) & 15;
    int wave = threadIdx.x >> 6;
    int lane = threadIdx.x & 63;
    int c = lane & 15, g = lane >> 4;
    int q0w = qt * 256 + wave * 64;          // 64 q-rows per wave

    bf16x8 qh[4][2], ql[4][2];
#pragma unroll
    for (int sub = 0; sub < 4; ++sub) {
        const size_t qo = ((size_t)b * SEQ + q0w + sub * 16 + c) * CH + g * 8;
        qh[sub][0] = *(const bf16x8*)(Qh + qo);
        qh[sub][1] = *(const bf16x8*)(Qh + qo + 32);
        ql[sub][0] = *(const bf16x8*)(Ql + qo);
        ql[sub][1] = *(const bf16x8*)(Ql + qo + 32);
    }

    f32x4 o[4][4];
#pragma unroll
    for (int sub = 0; sub < 4; ++sub)
#pragma unroll
        for (int nt = 0; nt < 4; ++nt) o[sub][nt] = (f32x4){0.f, 0.f, 0.f, 0.f};
    float m[4] = {-1e30f, -1e30f, -1e30f, -1e30f};
    float l[4] = {0.f, 0.f, 0.f, 0.f};

    const unsigned short* Kbh = Kh + (size_t)b * SEQ * CH;
    const unsigned short* Kbl = Kl + (size_t)b * SEQ * CH;
    const unsigned short* Vb  = Vt + (size_t)b * CH * SEQ;

    const int prow = ((c >> 2) << 3) + (c & 3);   // permuted key row (octet low)

    bf16x8 KA[4], EA[4], KB[4], EB[4];
    bf16x8 vf0, vf1, vf2, vf3;

    int kbeg = s * seg_len;
    int nt2  = seg_len >> 6;                // pairs of 32-key tiles
    int kb   = kbeg;

    LOADK(KA, EA, kbeg);
    for (int it = 0; it < nt2 - 1; ++it, kb += 64) {
        PREV(kb);
        LOADK(KB, EB, kb + 32);
        COMPUTE4(KA, EA);
        PREV(kb + 32);
        LOADK(KA, EA, kb + 64);
        COMPUTE4(KB, EB);
    }
    PREV(kb);
    LOADK(KB, EB, kb + 32);
    COMPUTE4(KA, EA);
    PREV(kb + 32);
    COMPUTE4(KB, EB);

    // deferred cross-g l reduction (per query c within each sub-tile)
#pragma unroll
    for (int sub = 0; sub < 4; ++sub) {
        l[sub] += __shfl_xor(l[sub], 16);
        l[sub] += __shfl_xor(l[sub], 32);
    }

    float* Ob = Opart + (size_t)s * ((size_t)BATCH * SEQ * CH) + ((size_t)b * SEQ + q0w) * CH;
#pragma unroll
    for (int sub = 0; sub < 4; ++sub) {
#pragma unroll
        for (int r = 0; r < 4; ++r) {
            size_t row = (size_t)(sub * 16 + g * 4 + r) * CH;
#pragma unroll
            for (int nt = 0; nt < 4; ++nt)
                __builtin_nontemporal_store(o[sub][nt][r], &Ob[row + nt * 16 + c]);
        }
    }
    if (g == 0) {
#pragma unroll
        for (int sub = 0; sub < 4; ++sub) {
            int row = b * SEQ + q0w + sub * 16 + c;
            __builtin_nontemporal_store(m[sub], &Mp[s * (BATCH * SEQ) + row]);
            __builtin_nontemporal_store(l[sub], &Lp[s * (BATCH * SEQ) + row]);
        }
    }
}

// ---------------------------------------------------------------------------
// K3: fused epilogue — LSE-combine split partials, convert to bf16 hi/lo in
// LDS, then 1x1 output conv via MFMA (3-product split, ~fp32). Writes fp32.
// grid: 512 blocks (64 rows each), 256 threads.
// ---------------------------------------------------------------------------
__global__ __launch_bounds__(256) void fuse_out_kernel(
        const float* __restrict__ Opart, const float* __restrict__ Mp,
        const float* __restrict__ Lp,
        const unsigned short* __restrict__ Woth, const unsigned short* __restrict__ Wotl,
        const float* __restrict__ bo, float* __restrict__ out, int nsplit) {
    int blk = blockIdx.x;
    int b  = blk >> 6;
    int l0 = (blk & 63) << 6;

    __shared__ unsigned short xh[64][64];
    __shared__ unsigned short xl[64][64];
    __shared__ float wf[4][64];
    __shared__ float ivd[64];

    int tid = threadIdx.x;
    if (tid < 64) {
        int row = b * SEQ + l0 + tid;
        float M = -1e30f;
        for (int s2 = 0; s2 < nsplit; ++s2) M = fmaxf(M, Mp[s2 * (BATCH * SEQ) + row]);
        float den = 0.f;
        for (int s2 = 0; s2 < nsplit; ++s2) {
            float w = exp2f(Mp[s2 * (BATCH * SEQ) + row] - M);
            wf[s2][tid] = w;
            den = fmaf(w, Lp[s2 * (BATCH * SEQ) + row], den);
        }
        ivd[tid] = 1.f / den;
    }
    __syncthreads();

    for (int idx = tid; idx < 64 * 16; idx += 256) {
        int row = idx >> 4, i = (idx & 15) << 2;
        size_t base = ((size_t)b * SEQ + l0 + row) * CH + i;
        float4 a = make_float4(0.f, 0.f, 0.f, 0.f);
        for (int s2 = 0; s2 < nsplit; ++s2) {
            float w = wf[s2][row];
            float4 v = *(const float4*)(Opart + (size_t)s2 * ((size_t)BATCH * SEQ * CH) + base);
            a.x = fmaf(w, v.x, a.x); a.y = fmaf(w, v.y, a.y);
            a.z = fmaf(w, v.z, a.z); a.w = fmaf(w, v.w, a.w);
        }
        float iv = ivd[row];
        a.x *= iv; a.y *= iv; a.z *= iv; a.w *= iv;
        unsigned hp0 = cvtpk(a.x, a.y), hp1 = cvtpk(a.z, a.w);
        float b0 = __uint_as_float(hp0 << 16), b1 = __uint_as_float(hp0 & 0xffff0000u);
        float b2 = __uint_as_float(hp1 << 16), b3 = __uint_as_float(hp1 & 0xffff0000u);
        unsigned lp0 = cvtpk(a.x - b0, a.y - b1), lp1 = cvtpk(a.z - b2, a.w - b3);
        int sw = i ^ ((row & 7) << 3);
        uint2 hp = { hp0, hp1 }, lp = { lp0, lp1 };
        *(uint2*)&xh[row][sw] = hp;
        *(uint2*)&xl[row][sw] = lp;
    }
    __syncthreads();

    int wave = tid >> 6, lane = tid & 63;
    int g = lane >> 4, cc = lane & 15;
    int wrow0 = wave << 4;

    bf16x8 ah[2], al[2];
#pragma unroll
    for (int kk = 0; kk < 2; ++kk) {
        int u = wrow0 + cc;
        int blk2 = ((kk * 4 + g) ^ (u & 7));
        ah[kk] = *(const bf16x8*)&xh[u][blk2 << 3];
        al[kk] = *(const bf16x8*)&xl[u][blk2 << 3];
    }

    for (int nt = 0; nt < 4; ++nt) {
        int col = nt * 16 + cc;
        f32x4 acc = {0.f, 0.f, 0.f, 0.f};
#pragma unroll
        for (int kk = 0; kk < 2; ++kk) {
            bf16x8 bh = *(const bf16x8*)(Woth + col * CH + kk * 32 + g * 8);
            bf16x8 bl = *(const bf16x8*)(Wotl + col * CH + kk * 32 + g * 8);
            acc = MFMA16(ah[kk], bh, acc);
            acc = MFMA16(al[kk], bh, acc);
            acc = MFMA16(ah[kk], bl, acc);
        }
        float bias = bo[col];
#pragma unroll
        for (int r = 0; r < 4; ++r)
            out[((size_t)b * SEQ + l0 + wrow0 + g * 4 + r) * CH + col] = acc[r] + bias;
    }
}

// ---------------------------------------------------------------------------
extern "C" void kernel_launch(void* const* d_in, const int* in_sizes, int n_in,
                              void* d_out, int out_size, void* d_ws, size_t ws_size,
                              hipStream_t stream) {
    (void)in_sizes; (void)n_in; (void)out_size;
    const float* Q  = (const float*)d_in[0];
    const float* K  = (const float*)d_in[1];
    const float* V  = (const float*)d_in[2];
    const float* wq = (const float*)d_in[3];
    const float* bq = (const float*)d_in[4];
    const float* wk = (const float*)d_in[5];
    const float* bk = (const float*)d_in[6];
    const float* wv = (const float*)d_in[7];
    const float* bv = (const float*)d_in[8];
    const float* wd = (const float*)d_in[9];
    const float* bd = (const float*)d_in[10];
    const float* wo = (const float*)d_in[11];
    const float* bo = (const float*)d_in[12];
    float* out = (float*)d_out;

    const size_t NEL = (size_t)BATCH * SEQ * CH;   // 2097152
    char* ws = (char*)d_ws;
    unsigned short* Wth = (unsigned short*)(ws);                 // 73728 B
    unsigned short* Wtl = (unsigned short*)(ws + 73728);         // 73728 B
    float* bbp = (float*)(ws + 147456);                          // 2304 B
    unsigned short* Qh = (unsigned short*)(ws + 163840);
    unsigned short* Ql = Qh + NEL;
    unsigned short* Kh = Ql + NEL;
    unsigned short* Kl = Kh + NEL;
    unsigned short* Vt = Kl + NEL;                               // ends at 21135360

    unsigned short* Woth = (unsigned short*)(ws + 21135360);     // 8192 B
    unsigned short* Wotl = (unsigned short*)(ws + 21143552);     // 8192 B
    float* Mp    = (float*)(ws + 21151744);                      // 4*131072 B
    float* Lp    = (float*)(ws + 21676032);                      // 4*131072 B
    float* Opart = (float*)(ws + 22200320);                      // NS*8388608 B

    const size_t NEED4 = 22200320 + 4u * 8388608;   // 55754752
    const size_t NEED2 = 22200320 + 2u * 8388608;
    int NS = (ws_size >= NEED4) ? 4 : (ws_size >= NEED2) ? 2 : 1;

    combine_w_kernel<<<10, 256, 0, stream>>>(wq, bq, wk, bk, wv, bv, wd, wo,
                                             Wth, Wtl, bbp, Woth, Wotl);
    conv_mfma_kernel<<<dim3(512, 3), 256, 0, stream>>>(
        Q, K, V, Wth, Wtl, bbp, bd, Qh, Ql, Kh, Kl, Vt);
    attn_kernel<<<128 * NS, 256, 0, stream>>>(
        Qh, Ql, Kh, Kl, Vt, Opart, Mp, Lp, SEQ / NS);
    fuse_out_kernel<<<512, 256, 0, stream>>>(Opart, Mp, Lp, Woth, Wotl, bo, out, NS);
}